// Round 1
// baseline (1130.528 us; speedup 1.0000x reference)
//
#include <hip/hip_runtime.h>
#include <math.h>

#define B_ 128
#define C_ 273
#define T_ 2048
#define O_ 270
#define D_ 288
#define NFREQ 12

// ---------------------------------------------------------------------------
// K1: Fourier embedding. emb[b,c,k] = cos(loc_k), emb[b,c,144+k] = sin(loc_k)
// loc[i,j] = (pos_x+0.2)*p[i] + (pos_y+0.2)*p[j], p[i] = (2pi/1.4)*i
// ---------------------------------------------------------------------------
__global__ __launch_bounds__(256) void k_emb(const float* __restrict__ pos,
                                             float* __restrict__ emb) {
    int idx = blockIdx.x * blockDim.x + threadIdx.x;
    const int total = B_ * C_ * 144;
    if (idx >= total) return;
    int bc = idx / 144;
    int k  = idx - bc * 144;
    int i  = k / NFREQ;
    int j  = k - i * NFREQ;
    float px = pos[bc * 2 + 0] + 0.2f;
    float py = pos[bc * 2 + 1] + 0.2f;
    const float w0 = 4.48798950512827605f; // 2*pi/1.4
    float loc = px * (w0 * (float)i) + py * (w0 * (float)j);
    float s, c;
    sincosf(loc, &s, &c);
    emb[(size_t)bc * D_ + k]       = c;
    emb[(size_t)bc * D_ + 144 + k] = s;
}

// ---------------------------------------------------------------------------
// K2: scores[b,o,c] = sum_d heads[sid[b],o,d] * emb[b,c,d]
// 64x64 tile, 256 threads, 4x4 per thread, BK=16. K=288 divides evenly.
// ---------------------------------------------------------------------------
#define BK2 16
__global__ __launch_bounds__(256) void k_scores(const float* __restrict__ emb,
                                                const float* __restrict__ heads,
                                                const int* __restrict__ sids,
                                                float* __restrict__ scores) {
    __shared__ __align__(16) float Hs[BK2][68];  // [k][o_local], pad 4 keeps 16B align
    __shared__ __align__(16) float Es[BK2][68];  // [k][c_local]
    int b     = blockIdx.z;
    int otile = blockIdx.y * 64;
    int ctile = blockIdx.x * 64;
    int sid   = sids[b];
    int tid   = threadIdx.x;
    int ty = tid >> 4;      // o group 0..15
    int tx = tid & 15;      // c group 0..15
    float acc[4][4] = {};
    const float* hbase = heads + (size_t)sid * O_ * D_;
    const float* ebase = emb + (size_t)b * C_ * D_;
    int lrow = tid >> 2;          // 0..63
    int lk4  = (tid & 3) * 4;     // 0,4,8,12

    for (int k0 = 0; k0 < D_; k0 += BK2) {
        {
            int o = otile + lrow;
            float4 v = make_float4(0.f, 0.f, 0.f, 0.f);
            if (o < O_) v = *(const float4*)(hbase + (size_t)o * D_ + k0 + lk4);
            Hs[lk4 + 0][lrow] = v.x; Hs[lk4 + 1][lrow] = v.y;
            Hs[lk4 + 2][lrow] = v.z; Hs[lk4 + 3][lrow] = v.w;
            int c = ctile + lrow;
            float4 e = make_float4(0.f, 0.f, 0.f, 0.f);
            if (c < C_) e = *(const float4*)(ebase + (size_t)c * D_ + k0 + lk4);
            Es[lk4 + 0][lrow] = e.x; Es[lk4 + 1][lrow] = e.y;
            Es[lk4 + 2][lrow] = e.z; Es[lk4 + 3][lrow] = e.w;
        }
        __syncthreads();
        #pragma unroll
        for (int k = 0; k < BK2; ++k) {
            float4 av = *(const float4*)&Hs[k][ty * 4];
            float4 ev = *(const float4*)&Es[k][tx * 4];
            float a[4] = {av.x, av.y, av.z, av.w};
            float e[4] = {ev.x, ev.y, ev.z, ev.w};
            #pragma unroll
            for (int i = 0; i < 4; ++i)
                #pragma unroll
                for (int j = 0; j < 4; ++j)
                    acc[i][j] += a[i] * e[j];
        }
        __syncthreads();
    }
    #pragma unroll
    for (int i = 0; i < 4; ++i) {
        int o = otile + ty * 4 + i;
        if (o >= O_) continue;
        #pragma unroll
        for (int j = 0; j < 4; ++j) {
            int c = ctile + tx * 4 + j;
            if (c < C_) scores[((size_t)b * O_ + o) * C_ + c] = acc[i][j];
        }
    }
}

// ---------------------------------------------------------------------------
// K3: softmax over c (in place), with invalid-position mask.
// One wave per (b,o) row; 4 waves per block; shfl-only reduction.
// ---------------------------------------------------------------------------
__global__ __launch_bounds__(256) void k_softmax(float* __restrict__ scores,
                                                 const float* __restrict__ pos) {
    int wave = threadIdx.x >> 6;
    int lane = threadIdx.x & 63;
    int row  = blockIdx.x * 4 + wave;   // over B_*O_
    if (row >= B_ * O_) return;
    int b = row / O_;
    float* srow = scores + (size_t)row * C_;
    const float* prow = pos + (size_t)b * C_ * 2;

    float v[5];
    float m = -INFINITY;
    #pragma unroll
    for (int ch = 0; ch < 5; ++ch) {
        int c = lane + ch * 64;
        float s = -INFINITY;
        if (c < C_) {
            s = srow[c];
            float px = prow[c * 2], py = prow[c * 2 + 1];
            if (px == -0.1f && py == -0.1f) s = -INFINITY;
        }
        v[ch] = s;
        m = fmaxf(m, s);
    }
    #pragma unroll
    for (int off = 32; off; off >>= 1) m = fmaxf(m, __shfl_xor(m, off, 64));
    float sum = 0.f;
    #pragma unroll
    for (int ch = 0; ch < 5; ++ch) {
        v[ch] = expf(v[ch] - m);           // exp(-inf - m) = 0 for masked/oob
        if (lane + ch * 64 < C_) sum += v[ch];
    }
    #pragma unroll
    for (int off = 32; off; off >>= 1) sum += __shfl_xor(sum, off, 64);
    float inv = 1.0f / sum;
    #pragma unroll
    for (int ch = 0; ch < 5; ++ch) {
        int c = lane + ch * 64;
        if (c < C_) srow[c] = v[ch] * inv;
    }
}

// ---------------------------------------------------------------------------
// K4: out[b,o,t] = sum_c meg[b,c,t] * w[b,o,c]
// Tile: 64 (o) x 128 (t), BK=16 over c. 256 threads, 4(o) x 8(t) per thread.
// Thread's t-cols split as tx*4 and tx*4+64 -> all LDS b128 reads 2-way max.
// ---------------------------------------------------------------------------
#define BK4 16
__global__ __launch_bounds__(256) void k_out(const float* __restrict__ meg,
                                             const float* __restrict__ wts,
                                             float* __restrict__ out) {
    __shared__ __align__(16) float Ws[BK4][68];   // [k][o_local]
    __shared__ __align__(16) float Ms[BK4][132];  // [k][t_local], pad 4
    int b     = blockIdx.z;
    int otile = blockIdx.y * 64;
    int t0    = blockIdx.x * 128;
    int tid   = threadIdx.x;
    int tx = tid & 15;   // t group
    int ty = tid >> 4;   // o group
    float acc[4][8] = {};
    const float* wbase = wts + (size_t)b * O_ * C_;
    const float* mbase = meg + (size_t)b * C_ * T_;
    int lrow = tid >> 2;
    int lk4  = (tid & 3) * 4;

    for (int c0 = 0; c0 < C_; c0 += BK4) {
        // W tile (scalar, guarded: C_=273 is odd so rows are unaligned)
        {
            int o = otile + lrow;
            #pragma unroll
            for (int q = 0; q < 4; ++q) {
                int c = c0 + lk4 + q;
                float w = (o < O_ && c < C_) ? wbase[(size_t)o * C_ + c] : 0.f;
                Ws[lk4 + q][lrow] = w;
            }
        }
        // M tile: 16 rows x 128 t, float4 along t (aligned: T_=2048)
        #pragma unroll
        for (int rr = 0; rr < 2; ++rr) {
            int idx = tid + rr * 256;
            int k   = idx >> 5;           // 0..15
            int t4  = (idx & 31) * 4;     // 0..124
            int c   = c0 + k;
            float4 v = make_float4(0.f, 0.f, 0.f, 0.f);
            if (c < C_) v = *(const float4*)(mbase + (size_t)c * T_ + t0 + t4);
            *(float4*)&Ms[k][t4] = v;
        }
        __syncthreads();
        #pragma unroll
        for (int k = 0; k < BK4; ++k) {
            float4 av  = *(const float4*)&Ws[k][ty * 4];
            float4 b0v = *(const float4*)&Ms[k][tx * 4];
            float4 b1v = *(const float4*)&Ms[k][tx * 4 + 64];
            float a[4]  = {av.x, av.y, av.z, av.w};
            float bb[8] = {b0v.x, b0v.y, b0v.z, b0v.w, b1v.x, b1v.y, b1v.z, b1v.w};
            #pragma unroll
            for (int i = 0; i < 4; ++i)
                #pragma unroll
                for (int j = 0; j < 8; ++j)
                    acc[i][j] += a[i] * bb[j];
        }
        __syncthreads();
    }
    #pragma unroll
    for (int i = 0; i < 4; ++i) {
        int o = otile + ty * 4 + i;
        if (o >= O_) continue;
        float* orow = out + ((size_t)b * O_ + o) * T_ + t0;
        *(float4*)(orow + tx * 4)      = make_float4(acc[i][0], acc[i][1], acc[i][2], acc[i][3]);
        *(float4*)(orow + tx * 4 + 64) = make_float4(acc[i][4], acc[i][5], acc[i][6], acc[i][7]);
    }
}

// ---------------------------------------------------------------------------
extern "C" void kernel_launch(void* const* d_in, const int* in_sizes, int n_in,
                              void* d_out, int out_size, void* d_ws, size_t ws_size,
                              hipStream_t stream) {
    const float* meg   = (const float*)d_in[0];
    const float* pos   = (const float*)d_in[1];
    const int*   sids  = (const int*)d_in[2];
    const float* heads = (const float*)d_in[3];
    float* out = (float*)d_out;

    // workspace layout: emb [B*C*288] fp32 (40.3 MB) | scores [B*O*C] fp32 (37.7 MB)
    float* emb    = (float*)d_ws;
    float* scores = emb + (size_t)B_ * C_ * D_;

    int total1 = B_ * C_ * 144;
    k_emb<<<(total1 + 255) / 256, 256, 0, stream>>>(pos, emb);
    k_scores<<<dim3(5, 5, B_), 256, 0, stream>>>(emb, heads, sids, scores);
    k_softmax<<<(B_ * O_ + 3) / 4, 256, 0, stream>>>(scores, pos);
    k_out<<<dim3(T_ / 128, 5, B_), 256, 0, stream>>>(meg, scores, out);
}

// Round 2
// 670.912 us; speedup vs baseline: 1.6851x; 1.6851x over previous
//
#include <hip/hip_runtime.h>
#include <math.h>

#define B_ 128
#define C_ 273
#define T_ 2048
#define O_ 270
#define D_ 288   // fourier dim; also the K of k_scores
#define OP_ 288  // O padded to multiple of 96/16
#define CP_ 384  // C padded to 3*128 (emb rows, N of k_scores)
#define KP_ 288  // C padded to multiple of 32 (K of k_out)

typedef __attribute__((ext_vector_type(8))) short short8;  // 8 x bf16 (4 VGPR)
typedef __attribute__((ext_vector_type(4))) float f32x4;   // MFMA acc

__device__ inline ushort f2bf(float f) {  // RNE fp32 -> bf16
    uint u = __float_as_uint(f);
    return (ushort)((u + 0x7FFFu + ((u >> 16) & 1u)) >> 16);
}
__device__ inline uint pack2bf(float lo, float hi) {
    return (uint)f2bf(lo) | ((uint)f2bf(hi) << 16);
}

// ---------------------------------------------------------------------------
// K1: Fourier embedding -> bf16, padded rows [B][CP_][288], rows c>=273 zero.
// ---------------------------------------------------------------------------
__global__ __launch_bounds__(256) void k_emb(const float* __restrict__ pos,
                                             ushort* __restrict__ emb) {
    int idx = blockIdx.x * 256 + threadIdx.x;
    const int total = B_ * CP_ * 144;
    if (idx >= total) return;
    int bc = idx / 144;
    int k  = idx - bc * 144;
    int b  = bc / CP_;
    int c  = bc - b * CP_;
    ushort* row = emb + ((size_t)b * CP_ + c) * D_;
    if (c >= C_) { row[k] = 0; row[144 + k] = 0; return; }
    int i = k / 12, j = k - i * 12;
    float px = pos[((size_t)b * C_ + c) * 2 + 0] + 0.2f;
    float py = pos[((size_t)b * C_ + c) * 2 + 1] + 0.2f;
    const float w0 = 4.48798950512827605f; // 2*pi/1.4
    float loc = px * (w0 * (float)i) + py * (w0 * (float)j);
    float s, cc;
    sincosf(loc, &s, &cc);
    row[k]       = f2bf(cc);
    row[144 + k] = f2bf(s);
}

// ---------------------------------------------------------------------------
// K2: gather per-subject heads -> bf16 [B][OP_][288], rows o>=270 zero.
// ---------------------------------------------------------------------------
__global__ __launch_bounds__(256) void k_gather(const float* __restrict__ heads,
                                                const int* __restrict__ sids,
                                                ushort* __restrict__ hb) {
    int idx = blockIdx.x * 256 + threadIdx.x;
    const int total = B_ * OP_ * (D_ / 8);
    if (idx >= total) return;
    int d8 = (idx % 36) * 8;
    int t  = idx / 36;
    int o  = t % OP_;
    int b  = t / OP_;
    uint4 outv = make_uint4(0, 0, 0, 0);
    if (o < O_) {
        int sid = sids[b];
        const float* src = heads + ((size_t)sid * O_ + o) * D_ + d8;
        float4 v0 = *(const float4*)src;
        float4 v1 = *(const float4*)(src + 4);
        outv.x = pack2bf(v0.x, v0.y); outv.y = pack2bf(v0.z, v0.w);
        outv.z = pack2bf(v1.x, v1.y); outv.w = pack2bf(v1.z, v1.w);
    }
    *(uint4*)(hb + ((size_t)b * OP_ + o) * D_ + d8) = outv;
}

// ---------------------------------------------------------------------------
// K3: scores = hb @ emb^T  (bf16 MFMA, M=270->288, N=273->384, K=288)
// Block: 96(M) x 128(N), 4 waves (2x2), wave = 48x64 = 3x4 MFMA 16x16x32.
// ---------------------------------------------------------------------------
__global__ __launch_bounds__(256) void k_scores(const ushort* __restrict__ hb,
                                                const ushort* __restrict__ emb,
                                                float* __restrict__ scores) {
    __shared__ uint AsU[96 * 16];   // 96 rows x 32 bf16 (64 B rows)
    __shared__ uint BsU[128 * 16];  // 128 rows x 32 bf16
    int b  = blockIdx.z;
    int o0 = blockIdx.y * 96;
    int n0 = blockIdx.x * 128;
    int tid = threadIdx.x;
    int wid = tid >> 6, lane = tid & 63;
    int wm = wid >> 1, wn = wid & 1;
    int lm = lane & 15, lq = lane >> 4;
    const ushort* Ab = hb  + (size_t)b * OP_ * D_;
    const ushort* Bb = emb + (size_t)b * CP_ * D_;
    f32x4 acc[3][4];
    #pragma unroll
    for (int i = 0; i < 3; ++i)
        #pragma unroll
        for (int j = 0; j < 4; ++j) { f32x4 z = {0.f, 0.f, 0.f, 0.f}; acc[i][j] = z; }

    for (int k0 = 0; k0 < D_; k0 += 32) {
        { // A tile: 96x32 bf16 = 384 16B slots
            int row = tid >> 2, ch = tid & 3;
            uint4 v = *(const uint4*)(Ab + (size_t)(o0 + row) * D_ + k0 + ch * 8);
            *(uint4*)&AsU[tid * 4] = v;
            if (tid < 128) {
                int s2 = 256 + tid, row2 = s2 >> 2, ch2 = s2 & 3;
                uint4 v2 = *(const uint4*)(Ab + (size_t)(o0 + row2) * D_ + k0 + ch2 * 8);
                *(uint4*)&AsU[s2 * 4] = v2;
            }
        }
        #pragma unroll
        for (int it = 0; it < 2; ++it) { // B tile: 128x32 = 512 slots
            int slot = tid + it * 256;
            int row = slot >> 2, ch = slot & 3;
            uint4 v = *(const uint4*)(Bb + (size_t)(n0 + row) * D_ + k0 + ch * 8);
            *(uint4*)&BsU[slot * 4] = v;
        }
        __syncthreads();
        short8 a[3], bb[4];
        #pragma unroll
        for (int fm = 0; fm < 3; ++fm)
            a[fm] = *(short8*)((ushort*)AsU + (wm * 48 + fm * 16 + lm) * 32 + lq * 8);
        #pragma unroll
        for (int fn = 0; fn < 4; ++fn)
            bb[fn] = *(short8*)((ushort*)BsU + (wn * 64 + fn * 16 + lm) * 32 + lq * 8);
        #pragma unroll
        for (int fm = 0; fm < 3; ++fm)
            #pragma unroll
            for (int fn = 0; fn < 4; ++fn)
                acc[fm][fn] = __builtin_amdgcn_mfma_f32_16x16x32_bf16(a[fm], bb[fn], acc[fm][fn], 0, 0, 0);
        __syncthreads();
    }
    // D layout: row(m) = lq*4 + reg, col(n) = lm   [verified m89/m91]
    #pragma unroll
    for (int fm = 0; fm < 3; ++fm) {
        int obase = o0 + wm * 48 + fm * 16 + lq * 4;
        #pragma unroll
        for (int fn = 0; fn < 4; ++fn) {
            int c = n0 + wn * 64 + fn * 16 + lm;
            if (c >= C_) continue;
            #pragma unroll
            for (int r = 0; r < 4; ++r) {
                int o = obase + r;
                if (o < O_) scores[((size_t)b * O_ + o) * C_ + c] = acc[fm][fn][r];
            }
        }
    }
}

// ---------------------------------------------------------------------------
// K4: softmax over c; writes bf16 weights [B][OP_][KP_], pads zeroed.
// ---------------------------------------------------------------------------
__global__ __launch_bounds__(256) void k_softmax(const float* __restrict__ scores,
                                                 const float* __restrict__ pos,
                                                 ushort* __restrict__ wbf) {
    int wave = threadIdx.x >> 6, lane = threadIdx.x & 63;
    int row = blockIdx.x * 4 + wave;   // over B_*OP_
    if (row >= B_ * OP_) return;
    int b = row / OP_, o = row - b * OP_;
    ushort* wrow = wbf + ((size_t)b * OP_ + o) * KP_;
    if (o >= O_) {
        #pragma unroll
        for (int ch = 0; ch < 5; ++ch) { int c = lane + ch * 64; if (c < KP_) wrow[c] = 0; }
        return;
    }
    const float* srow = scores + ((size_t)b * O_ + o) * C_;
    const float* prow = pos + (size_t)b * C_ * 2;
    float v[5];
    float m = -INFINITY;
    #pragma unroll
    for (int ch = 0; ch < 5; ++ch) {
        int c = lane + ch * 64;
        float s = -INFINITY;
        if (c < C_) {
            s = srow[c];
            float px = prow[c * 2], py = prow[c * 2 + 1];
            if (px == -0.1f && py == -0.1f) s = -INFINITY;
        }
        v[ch] = s;
        m = fmaxf(m, s);
    }
    #pragma unroll
    for (int off = 32; off; off >>= 1) m = fmaxf(m, __shfl_xor(m, off, 64));
    float sum = 0.f;
    #pragma unroll
    for (int ch = 0; ch < 5; ++ch) {
        v[ch] = expf(v[ch] - m);
        if (lane + ch * 64 < C_) sum += v[ch];
    }
    #pragma unroll
    for (int off = 32; off; off >>= 1) sum += __shfl_xor(sum, off, 64);
    float inv = 1.0f / sum;
    #pragma unroll
    for (int ch = 0; ch < 5; ++ch) {
        int c = lane + ch * 64;
        if (c < C_) wrow[c] = f2bf(v[ch] * inv);
        else if (c < KP_) wrow[c] = 0;
    }
}

// ---------------------------------------------------------------------------
// K5: out = w @ meg  (bf16 MFMA). A = wbf (K-contig). B staged with in-LDS
// fp32->bf16 transpose of meg[c][t]. M=270->288, N=2048, K=288 (c-pad zero).
// ---------------------------------------------------------------------------
__global__ __launch_bounds__(256) void k_out(const float* __restrict__ meg,
                                             const ushort* __restrict__ wbf,
                                             float* __restrict__ out) {
    __shared__ uint AsU[96 * 16];   // 96 x 32 bf16
    __shared__ uint BsU[128 * 16];  // 128(t) x 32(c) bf16, transposed tile
    int b  = blockIdx.z;
    int o0 = blockIdx.y * 96;
    int t0 = blockIdx.x * 128;
    int tid = threadIdx.x;
    int wid = tid >> 6, lane = tid & 63;
    int wm = wid >> 1, wn = wid & 1;
    int lm = lane & 15, lq = lane >> 4;
    const ushort* Ab = wbf + (size_t)b * OP_ * KP_;
    const float*  Mb = meg + (size_t)b * C_ * T_;
    f32x4 acc[3][4];
    #pragma unroll
    for (int i = 0; i < 3; ++i)
        #pragma unroll
        for (int j = 0; j < 4; ++j) { f32x4 z = {0.f, 0.f, 0.f, 0.f}; acc[i][j] = z; }

    int cpair = tid & 15;   // c pair index within 32-c k-slice
    int tq0   = tid >> 4;   // 0..15 (iter1 adds 16)

    for (int k0 = 0; k0 < KP_; k0 += 32) {
        { // A tile from wbf (bf16, K-contiguous)
            int row = tid >> 2, ch = tid & 3;
            uint4 v = *(const uint4*)(Ab + (size_t)(o0 + row) * KP_ + k0 + ch * 8);
            *(uint4*)&AsU[tid * 4] = v;
            if (tid < 128) {
                int s2 = 256 + tid, row2 = s2 >> 2, ch2 = s2 & 3;
                uint4 v2 = *(const uint4*)(Ab + (size_t)(o0 + row2) * KP_ + k0 + ch2 * 8);
                *(uint4*)&AsU[s2 * 4] = v2;
            }
        }
        // B tile: transpose meg[c0..c0+32)[t0..t0+128) fp32 -> Bs[t][c] bf16
        #pragma unroll
        for (int it = 0; it < 2; ++it) {
            int tqq = tq0 + it * 16;         // 0..31
            int c   = k0 + cpair * 2;
            int t   = tqq * 4;
            float4 v0 = make_float4(0.f, 0.f, 0.f, 0.f);
            float4 v1 = make_float4(0.f, 0.f, 0.f, 0.f);
            if (c < C_)     v0 = *(const float4*)(Mb + (size_t)c * T_ + t0 + t);
            if (c + 1 < C_) v1 = *(const float4*)(Mb + (size_t)(c + 1) * T_ + t0 + t);
            BsU[(t + 0) * 16 + cpair] = pack2bf(v0.x, v1.x);
            BsU[(t + 1) * 16 + cpair] = pack2bf(v0.y, v1.y);
            BsU[(t + 2) * 16 + cpair] = pack2bf(v0.z, v1.z);
            BsU[(t + 3) * 16 + cpair] = pack2bf(v0.w, v1.w);
        }
        __syncthreads();
        short8 a[3], bb[4];
        #pragma unroll
        for (int fm = 0; fm < 3; ++fm)
            a[fm] = *(short8*)((ushort*)AsU + (wm * 48 + fm * 16 + lm) * 32 + lq * 8);
        #pragma unroll
        for (int fn = 0; fn < 4; ++fn)
            bb[fn] = *(short8*)((ushort*)BsU + (wn * 64 + fn * 16 + lm) * 32 + lq * 8);
        #pragma unroll
        for (int fm = 0; fm < 3; ++fm)
            #pragma unroll
            for (int fn = 0; fn < 4; ++fn)
                acc[fm][fn] = __builtin_amdgcn_mfma_f32_16x16x32_bf16(a[fm], bb[fn], acc[fm][fn], 0, 0, 0);
        __syncthreads();
    }
    #pragma unroll
    for (int fm = 0; fm < 3; ++fm) {
        int obase = o0 + wm * 48 + fm * 16 + lq * 4;
        #pragma unroll
        for (int fn = 0; fn < 4; ++fn) {
            int t = t0 + wn * 64 + fn * 16 + lm;
            #pragma unroll
            for (int r = 0; r < 4; ++r) {
                int o = obase + r;
                if (o < O_) out[((size_t)b * O_ + o) * T_ + t] = acc[fm][fn][r];
            }
        }
    }
}

// ---------------------------------------------------------------------------
extern "C" void kernel_launch(void* const* d_in, const int* in_sizes, int n_in,
                              void* d_out, int out_size, void* d_ws, size_t ws_size,
                              hipStream_t stream) {
    const float* meg   = (const float*)d_in[0];
    const float* pos   = (const float*)d_in[1];
    const int*   sids  = (const int*)d_in[2];
    const float* heads = (const float*)d_in[3];
    float* out = (float*)d_out;

    // ws: [emb_bf 28.3MB | hb 21.2MB | scores 37.7MB] = 87.3 MB
    // wbf aliases emb_bf (emb dead after k_scores).
    ushort* emb = (ushort*)d_ws;
    ushort* wbf = (ushort*)d_ws;
    ushort* hb  = emb + (size_t)B_ * CP_ * D_;
    float* scores = (float*)(hb + (size_t)B_ * OP_ * D_);

    k_emb<<<(B_ * CP_ * 144 + 255) / 256, 256, 0, stream>>>(pos, emb);
    k_gather<<<(B_ * OP_ * 36 + 255) / 256, 256, 0, stream>>>(heads, sids, hb);
    k_scores<<<dim3(3, 3, B_), 256, 0, stream>>>(hb, emb, scores);
    k_softmax<<<(B_ * OP_ + 3) / 4, 256, 0, stream>>>(scores, pos, wbf);
    k_out<<<dim3(T_ / 128, 3, B_), 256, 0, stream>>>(meg, wbf, out);
}